// Round 9
// baseline (2609.764 us; speedup 1.0000x reference)
//
#include <hip/hip_runtime.h>
#include <hip/hip_bf16.h>
#include <math.h>

// Node classifier: KProp(K=2, gcn_norm) -> SAGEConv(64->64)+selu -> SAGEConv(64->40) -> softmax
// N=100000, E=1600000, D=H=64, C=40. All fp32.
//
// R9: chunk-aligned props with a hardware ds_add_f32 engine.
//   - edges sorted by (strip = dst>>4, chunk = src>>13); strip = 16 dst nodes/wave,
//     16KB LDS acc per block (4 waves), wave-private slices.
//   - per edge: scalar csr load, scalar dis load, vector row load, ONE ds_add_f32
//     (inline asm, fire-and-forget; no branches, no CAS, no RAW chain).
//   - bucket_csr: counting sort over 64x13 keys + sdeg-based node stats.
//   - gemm: strided column ownership (col = tx + TX*c) kills the 4-way sW bank conflict.

#define RFL(x) __builtin_amdgcn_readfirstlane(x)
#define BK_SHIFT 10        // coarse bucket = dst>>10 (1024 nodes)
#define SSHIFT 4           // strip = 16 nodes per wave
#define CH_SHIFT 13        // src chunk = src>>13 (8192 rows = 2MB @ 64 floats)
#define NCHUNK 13          // ceil(100000/8192)
#define SPB 64             // strips per bucket = 1024/16
#define MAXBUCK 256

// ---------------- CSR build ----------------

__global__ void init_bcursor_kernel(int* __restrict__ bcursor, int nbuck, int cap) {
    int i = blockIdx.x * blockDim.x + threadIdx.x;
    if (i < nbuck) bcursor[i] = i * cap;
}

// Phase 1: block-private coarse bucket partition; packed u32 (src<<10 | dst&1023).
__global__ __launch_bounds__(256) void partition_kernel(const int* __restrict__ src,
                                                        const int* __restrict__ dst,
                                                        int* __restrict__ bcursor,
                                                        unsigned int* __restrict__ temp,
                                                        int e, int nbuck, int cap) {
    __shared__ int bc[MAXBUCK];
    int t = threadIdx.x;
    int chunk = (e + gridDim.x - 1) / gridDim.x;
    int base = blockIdx.x * chunk;
    int cnt = e - base;
    if (cnt > chunk) cnt = chunk;
    if (cnt < 0) cnt = 0;
    for (int j = t; j < nbuck; j += 256) bc[j] = 0;
    __syncthreads();
    for (int i = t; i < cnt; i += 256) {
        int d = dst[base + i];
        atomicAdd(&bc[d >> BK_SHIFT], 1);
    }
    __syncthreads();
    for (int j = t; j < nbuck; j += 256) {
        int c = bc[j];
        bc[j] = (c > 0) ? atomicAdd(&bcursor[j], c) : 0;
    }
    __syncthreads();
    for (int i = t; i < cnt; i += 256) {
        int s = src[base + i];
        int d = dst[base + i];
        int bk = d >> BK_SHIFT;
        int p = atomicAdd(&bc[bk], 1);
        if (p < (bk + 1) * cap) temp[p] = ((unsigned int)s << BK_SHIFT) | (unsigned int)(d & 1023);
    }
}

// Phase 2: per-bucket counting sort by (strip_local, chunk) + node stats.
// One WG (256 thr) per bucket of 1024 nodes = 64 strips of 16.
__global__ __launch_bounds__(256) void bucket_csr_kernel(const unsigned int* __restrict__ temp,
                                                         const int* __restrict__ bcursor,
                                                         float* __restrict__ dis,
                                                         float* __restrict__ cnt_inv,
                                                         unsigned int* __restrict__ csr,
                                                         int* __restrict__ strip_off,
                                                         int n, int cap, int nbuck, int e,
                                                         int nstrips) {
    __shared__ int sdeg[1024];
    __shared__ int cnt2[SPB * NCHUNK];   // 832
    __shared__ int part[256];
    __shared__ int stot[SPB];
    int b = blockIdx.x;
    int t = threadIdx.x;
    int nbeg = b << BK_SHIFT;
    // bbase = exclusive prefix of bucket counts
    int cj = 0;
    if (t < nbuck) {
        cj = bcursor[t] - t * cap;
        if (cj > cap) cj = cap;
    }
    part[t] = cj;
    __syncthreads();
    for (int off = 1; off < 256; off <<= 1) {
        int u = (t >= off) ? part[t - off] : 0;
        __syncthreads();
        part[t] += u;
        __syncthreads();
    }
    int cntb = bcursor[b] - b * cap;
    if (cntb > cap) cntb = cap;
    int bbase = part[b] - cntb;
    __syncthreads();
    // zero counters
    for (int i = t; i < 1024; i += 256) sdeg[i] = 0;
    for (int i = t; i < SPB * NCHUNK; i += 256) cnt2[i] = 0;
    __syncthreads();
    const unsigned int* tb = temp + (size_t)b * cap;
    for (int i = t; i < cntb; i += 256) {
        unsigned int ed = tb[i];
        int dstloc = (int)(ed & 1023u);
        int s = (int)(ed >> BK_SHIFT);
        atomicAdd(&sdeg[dstloc], 1);
        atomicAdd(&cnt2[(dstloc >> SSHIFT) * NCHUNK + (s >> CH_SHIFT)], 1);
    }
    __syncthreads();
    // node stats
#pragma unroll
    for (int k = 0; k < 4; ++k) {
        int idx = t * 4 + k;
        int node = nbeg + idx;
        if (node < n) {
            int d = sdeg[idx];
            float fd = (float)d;
            dis[node] = (d > 0) ? rsqrtf(fd) : 0.0f;
            cnt_inv[node] = 1.0f / fmaxf(fd, 1.0f);
        }
    }
    // strip totals + serial exclusive scan (64 entries)
    if (t < SPB) {
        int run = 0;
        for (int c = 0; c < NCHUNK; ++c) run += cnt2[t * NCHUNK + c];
        stot[t] = run;
    }
    __syncthreads();
    if (t == 0) {
        int run = 0;
        for (int sl = 0; sl < SPB; ++sl) {
            int v = stot[sl];
            stot[sl] = run;
            run += v;
        }
    }
    __syncthreads();
    if (t < SPB) {
        int run = stot[t];
        int gs = b * SPB + t;
        if (gs < nstrips) strip_off[gs] = bbase + run;
        for (int c = 0; c < NCHUNK; ++c) {
            int v = cnt2[t * NCHUNK + c];
            cnt2[t * NCHUNK + c] = run;
            run += v;
        }
    }
    if (b == nbuck - 1 && t == 0) strip_off[nstrips] = bbase + cntb;
    __syncthreads();
    // scatter: packed (src<<4 | node_local)
    for (int i = t; i < cntb; i += 256) {
        unsigned int ed = tb[i];
        int dstloc = (int)(ed & 1023u);
        int s = (int)(ed >> BK_SHIFT);
        int pos = atomicAdd(&cnt2[(dstloc >> SSHIFT) * NCHUNK + (s >> CH_SHIFT)], 1);
        csr[bbase + pos] = ((unsigned int)s << SSHIFT) | (unsigned int)(dstloc & 15);
    }
}

// ---------------- chunk-aligned propagation (ds_add_f32 engine) ----------------
// One wave per strip of 16 dst nodes; acc[16][64] fp32 wave-private in LDS.
// FW: input row width. USE_W: weight = dis[src].
// EPI: 0 = out*sc ; 1 = selu(acc*sc + r + bias) ; 2 = softmax(acc*sc + r), 40 cols.
template <int FW, bool USE_W, int EPI, int TAG>
__global__ __launch_bounds__(256) void propc3_kernel(const float* __restrict__ in,
                                                     float* __restrict__ out,
                                                     const int* __restrict__ strip_off,
                                                     const unsigned int* __restrict__ csr,
                                                     const float* __restrict__ dis,
                                                     const float* __restrict__ nscale,
                                                     const float* __restrict__ r_add,
                                                     const float* __restrict__ bias,
                                                     int n, int nstrips) {
    __shared__ float accs[4][16 * 64];
    int wid = threadIdx.x >> 6;
    int lane = threadIdx.x & 63;
    int strip = RFL((int)blockIdx.x * 4 + wid);
    if (strip >= nstrips) return;
    float* accw = accs[wid];
#pragma unroll
    for (int i = 0; i < 16; ++i) accw[i * 64 + lane] = 0.0f;
    asm volatile("" ::: "memory");   // keep zero-init above the ds_add asm
    // LDS byte address of this wave's slice (+lane): flat-pointer low 32 bits ARE the
    // LDS offset (AMD apertures are 2^32-aligned).
    unsigned lbase = (unsigned)(size_t)(accw + lane);
    int beg = RFL(strip_off[strip]);
    int end = RFL(strip_off[strip + 1]);
    const bool act = (FW == 64) || (lane < FW);
    int j = beg;
    for (; j + 8 <= end; j += 8) {
        unsigned int e[8];
#pragma unroll
        for (int q = 0; q < 8; ++q) e[q] = csr[j + q];   // uniform -> scalar loads
        float val[8];
        unsigned addr[8];
#pragma unroll
        for (int q = 0; q < 8; ++q) {
            int s = (int)(e[q] >> SSHIFT);
            float w = USE_W ? dis[s] : 1.0f;
            float v = act ? in[(size_t)s * FW + lane] : 0.0f;
            val[q] = w * v;
            addr[q] = lbase + ((e[q] & 15u) << 8);       // nl*64 floats = nl<<8 bytes
        }
#pragma unroll
        for (int q = 0; q < 8; ++q)
            asm volatile("ds_add_f32 %0, %1" :: "v"(addr[q]), "v"(val[q]));
    }
    for (; j < end; ++j) {
        unsigned int eq = csr[j];
        int s = (int)(eq >> SSHIFT);
        float w = USE_W ? dis[s] : 1.0f;
        float v = act ? in[(size_t)s * FW + lane] : 0.0f;
        float vv = w * v;
        unsigned a = lbase + ((eq & 15u) << 8);
        asm volatile("ds_add_f32 %0, %1" :: "v"(a), "v"(vv));
    }
    asm volatile("s_waitcnt lgkmcnt(0)" ::: "memory");   // drain ds_adds before reads
    // ---- epilogue ----
    int n0 = strip << SSHIFT;
    if (EPI == 0) {
#pragma unroll 4
        for (int nl = 0; nl < 16; ++nl) {
            int node = n0 + nl;
            if (node >= n) break;
            float sc = nscale[node];
            out[(size_t)node * 64 + lane] = accw[nl * 64 + lane] * sc;
        }
    } else if (EPI == 1) {
        float bb = bias[lane];
        const float scale = 1.0507009873554805f;
        const float alpha = 1.6732632423543772f;
#pragma unroll 4
        for (int nl = 0; nl < 16; ++nl) {
            int node = n0 + nl;
            if (node >= n) break;
            float sc = nscale[node];
            float tt = accw[nl * 64 + lane] * sc + r_add[(size_t)node * 64 + lane] + bb;
            tt = scale * (tt > 0.0f ? tt : alpha * expm1f(tt));
            out[(size_t)node * 64 + lane] = tt;
        }
    } else {
        for (int nl = 0; nl < 16; ++nl) {
            int node = n0 + nl;
            if (node >= n) break;
            float sc = nscale[node];
            float tt = 0.0f;
            if (lane < 40) tt = accw[nl * 64 + lane] * sc + r_add[(size_t)node * 40 + lane];
            float x = (lane < 40) ? tt : -INFINITY;
            float m = x;
            for (int off = 32; off; off >>= 1) m = fmaxf(m, __shfl_xor(m, off));
            float ex = (lane < 40) ? __expf(x - m) : 0.0f;
            float ss = ex;
            for (int off = 32; off; off >>= 1) ss += __shfl_xor(ss, off);
            if (lane < 40) out[(size_t)node * 40 + lane] = ex / ss;
        }
    }
}

// ---------------- tiled GEMM: [outL|outR] = in(64) @ [Wl|Wr] ----------------
// Strided column ownership (col = tx + TX*c): consecutive lanes -> consecutive
// banks on sW reads (R8 showed 4-way conflicts with blocked cols).
template <int OC, int CP>
__global__ __launch_bounds__(256) void gemm_kernel(const float* __restrict__ in,
                                                   const float* __restrict__ Wl,
                                                   const float* __restrict__ Wr,
                                                   const float* __restrict__ bias,
                                                   float* __restrict__ outL,
                                                   float* __restrict__ outR,
                                                   int n, int add_bias) {
    constexpr int HC = OC / 2;
    constexpr int TX = OC / CP;
    constexpr int TY = 256 / TX;
    constexpr int NPT = 64 / TY;
    constexpr int XP = 68;
    constexpr int WP = OC + 4;
    __shared__ float sXT[64 * XP];
    __shared__ float sW[64 * WP];
    int t = threadIdx.x;
    int blk = blockIdx.x;
    for (int i = 0; i < 16; ++i) {
        int idx = i * 256 + t;
        int nd = idx >> 6;
        int k = idx & 63;
        int ng = blk * 64 + nd;
        float v = in[(size_t)(ng < n ? ng : n - 1) * 64 + k];
        sXT[k * XP + nd] = v;
    }
    for (int i = t; i < 64 * HC; i += 256) {
        int k = i / HC;
        int c = i % HC;
        sW[k * WP + c] = Wl[i];
        sW[k * WP + HC + c] = Wr[i];
    }
    __syncthreads();
    int tx = t % TX;
    int ty = t / TX;
    float acc[NPT][CP];
#pragma unroll
    for (int i = 0; i < NPT; ++i)
#pragma unroll
        for (int c = 0; c < CP; ++c) acc[i][c] = 0.0f;
#pragma unroll 4
    for (int k = 0; k < 64; ++k) {
        float xv[NPT];
#pragma unroll
        for (int i = 0; i < NPT; ++i) xv[i] = sXT[k * XP + ty * NPT + i];
        float wv[CP];
#pragma unroll
        for (int c = 0; c < CP; ++c) wv[c] = sW[k * WP + tx + TX * c];
#pragma unroll
        for (int i = 0; i < NPT; ++i)
#pragma unroll
            for (int c = 0; c < CP; ++c) acc[i][c] += xv[i] * wv[c];
    }
#pragma unroll
    for (int i = 0; i < NPT; ++i) {
        int ng = blk * 64 + ty * NPT + i;
        if (ng >= n) break;
#pragma unroll
        for (int c = 0; c < CP; ++c) {
            int col = tx + TX * c;
            if (col < HC) {
                outL[(size_t)ng * HC + col] = acc[i][c];
            } else {
                float v = acc[i][c] + (add_bias ? bias[col - HC] : 0.0f);
                outR[(size_t)ng * HC + (col - HC)] = v;
            }
        }
    }
}

// ---------------- launch ----------------

extern "C" void kernel_launch(void* const* d_in, const int* in_sizes, int n_in,
                              void* d_out, int out_size, void* d_ws, size_t ws_size,
                              hipStream_t stream) {
    const float* x   = (const float*)d_in[0];
    const float* Wl1 = (const float*)d_in[1];
    const float* Wr1 = (const float*)d_in[2];
    const float* b1  = (const float*)d_in[3];
    const float* Wl2 = (const float*)d_in[4];
    const float* Wr2 = (const float*)d_in[5];
    const float* b2  = (const float*)d_in[6];
    const int* edge_src = (const int*)d_in[7];
    const int* edge_dst = (const int*)d_in[8];
    float* out = (float*)d_out;

    const int N = in_sizes[0] / 64;
    const int E = in_sizes[7];
    const int NBUCK = (N + (1 << BK_SHIFT) - 1) >> BK_SHIFT;   // 98
    const int NSTRIPS = (N + 15) >> SSHIFT;                    // 6250
    size_t bufC_bytes = (size_t)N * 64 * 4;
    int cap = E / NBUCK + E / (2 * NBUCK) + 1024;              // mean + 50% + slack
    int cap_max = (int)(bufC_bytes / ((size_t)NBUCK * 4));
    if (cap > cap_max) cap = cap_max;

    size_t off = 0;
    auto carve = [&](size_t bytes) -> void* {
        void* p = (char*)d_ws + off;
        off = (off + bytes + 255) & ~(size_t)255;
        return p;
    };
    int*          strip_off = (int*)carve((size_t)(NSTRIPS + 1) * 4);
    int*          bcursor   = (int*)carve((size_t)NBUCK * 4);
    float*        dis       = (float*)carve((size_t)N * 4);
    float*        cnt_inv   = (float*)carve((size_t)N * 4);
    unsigned int* csr       = (unsigned int*)carve((size_t)E * 4);
    float*        bufA      = (float*)carve((size_t)N * 64 * 4);
    float*        bufB      = (float*)carve((size_t)N * 64 * 4);
    float*        bufC      = (float*)carve(bufC_bytes);
    unsigned int* temp      = (unsigned int*)bufC;   // alias: dead before bufC written
    (void)ws_size;

    const int nb_prop = (NSTRIPS + 3) / 4;    // 1563 blocks, 4 strips each
    const int nb_gemm = (N + 63) / 64;

    // CSR build
    init_bcursor_kernel<<<(NBUCK + 255) / 256, 256, 0, stream>>>(bcursor, NBUCK, cap);
    partition_kernel<<<256, 256, 0, stream>>>(edge_src, edge_dst, bcursor, temp, E, NBUCK, cap);
    bucket_csr_kernel<<<NBUCK, 256, 0, stream>>>(temp, bcursor, dis, cnt_inv, csr, strip_off,
                                                 N, cap, NBUCK, E, NSTRIPS);

    // KProp x2: h = S (S x)
    propc3_kernel<64, true, 0, 1><<<nb_prop, 256, 0, stream>>>(x, bufA, strip_off, csr, dis, dis,
                                                               nullptr, nullptr, N, NSTRIPS);
    propc3_kernel<64, true, 0, 2><<<nb_prop, 256, 0, stream>>>(bufA, bufB, strip_off, csr, dis, dis,
                                                               nullptr, nullptr, N, NSTRIPS);
    // [t1|r1] = h @ [Wl1|Wr1]  (t1 -> bufA, r1 -> bufC)
    gemm_kernel<128, 8><<<nb_gemm, 256, 0, stream>>>(bufB, Wl1, Wr1, nullptr, bufA, bufC, N, 0);
    // h1 = selu(mean_agg(t1) + r1 + b1) -> bufB
    propc3_kernel<64, false, 1, 3><<<nb_prop, 256, 0, stream>>>(bufA, bufB, strip_off, csr, dis,
                                                                cnt_inv, bufC, b1, N, NSTRIPS);
    // [t2|r2+b2] = h1 @ [Wl2|Wr2]  (t2 -> bufA (N x 40), r2 -> bufC (N x 40))
    gemm_kernel<80, 5><<<nb_gemm, 256, 0, stream>>>(bufB, Wl2, Wr2, b2, bufA, bufC, N, 1);
    // out = softmax(mean_agg(t2) + r2)
    propc3_kernel<40, false, 2, 4><<<nb_prop, 256, 0, stream>>>(bufA, out, strip_off, csr, dis,
                                                                cnt_inv, bufC, nullptr, N, NSTRIPS);
}

// Round 10
// 464.102 us; speedup vs baseline: 5.6233x; 5.6233x over previous
//
#include <hip/hip_runtime.h>
#include <hip/hip_bf16.h>
#include <math.h>

// Node classifier: KProp(K=2, gcn_norm) -> SAGEConv(64->64)+selu -> SAGEConv(64->40) -> softmax
// N=100000, E=1600000, D=H=64, C=40. All fp32.
//
// R10 = R6's register-gather engine (best so far, 485us) + chunk-sorted rows:
//   each node's edge list is sorted by src chunk (src>>13). Co-resident waves all
//   walk rows front-to-back, so the machine sweeps src chunks ~in lockstep ->
//   passive L2 temporal alignment (R8 proved the fetch cut; its LDS engines lost it).
//   CSR build: block-private partition (u32-packed) + per-bucket counting sort over
//   (node_local x 13 chunks) keys; row_ptr/deg from the key prefix.
//   gemm keeps R9's strided-column fix (kills the 4-way sW bank conflict).

#define RFL(x) __builtin_amdgcn_readfirstlane(x)
#define BK_SHIFT 10        // coarse bucket = dst>>10 (1024 nodes)
#define CH_SHIFT 13        // src chunk = src>>13 (8192 rows = 2MB @ 64 floats)
#define NCHUNK 13          // ceil(100000/8192)
#define KPB2 (1024 * NCHUNK)   // sort keys per bucket
#define MAXBUCK 256

// ---------------- CSR build ----------------

__global__ void init_bcursor_kernel(int* __restrict__ bcursor, int nbuck, int cap) {
    int i = blockIdx.x * blockDim.x + threadIdx.x;
    if (i < nbuck) bcursor[i] = i * cap;
}

// Phase 1: block-private coarse bucket partition; packed u32 (src<<10 | dst&1023).
__global__ __launch_bounds__(256) void partition_kernel(const int* __restrict__ src,
                                                        const int* __restrict__ dst,
                                                        int* __restrict__ bcursor,
                                                        unsigned int* __restrict__ temp,
                                                        int e, int nbuck, int cap) {
    __shared__ int bc[MAXBUCK];
    int t = threadIdx.x;
    int chunk = (e + gridDim.x - 1) / gridDim.x;
    int base = blockIdx.x * chunk;
    int cnt = e - base;
    if (cnt > chunk) cnt = chunk;
    if (cnt < 0) cnt = 0;
    for (int j = t; j < nbuck; j += 256) bc[j] = 0;
    __syncthreads();
    for (int i = t; i < cnt; i += 256) {
        int d = dst[base + i];
        atomicAdd(&bc[d >> BK_SHIFT], 1);
    }
    __syncthreads();
    for (int j = t; j < nbuck; j += 256) {
        int c = bc[j];
        bc[j] = (c > 0) ? atomicAdd(&bcursor[j], c) : 0;
    }
    __syncthreads();
    for (int i = t; i < cnt; i += 256) {
        int s = src[base + i];
        int d = dst[base + i];
        int bk = d >> BK_SHIFT;
        int p = atomicAdd(&bc[bk], 1);
        if (p < (bk + 1) * cap) temp[p] = ((unsigned int)s << BK_SHIFT) | (unsigned int)(d & 1023);
    }
}

// Phase 2: per-bucket counting sort, key = node_local*13 + src_chunk.
// Emits row_ptr (node granularity), dis, cnt_inv, and csr_src sorted
// (node-major, chunk-ascending within node). One WG per bucket of 1024 nodes.
__global__ __launch_bounds__(256) void bucket_csr_kernel(const unsigned int* __restrict__ temp,
                                                         const int* __restrict__ bcursor,
                                                         int* __restrict__ row_ptr,
                                                         float* __restrict__ dis,
                                                         float* __restrict__ cnt_inv,
                                                         int* __restrict__ csr_src,
                                                         int n, int cap, int nbuck, int e) {
    __shared__ int cnt3[KPB2];     // 52KB: counts -> exclusive prefix -> cursors
    __shared__ int part[256];
    int b = blockIdx.x;
    int t = threadIdx.x;
    int nbeg = b << BK_SHIFT;
    // ---- bbase = exclusive prefix of bucket counts ----
    int cj = 0;
    if (t < nbuck) {
        cj = bcursor[t] - t * cap;
        if (cj > cap) cj = cap;
    }
    part[t] = cj;
    __syncthreads();
    for (int off = 1; off < 256; off <<= 1) {
        int u = (t >= off) ? part[t - off] : 0;
        __syncthreads();
        part[t] += u;
        __syncthreads();
    }
    int cntb = bcursor[b] - b * cap;
    if (cntb > cap) cntb = cap;
    int bbase = part[b] - cntb;
    __syncthreads();
    // ---- zero counters ----
    for (int i = t; i < KPB2; i += 256) cnt3[i] = 0;
    __syncthreads();
    // ---- count by (node_local, chunk) ----
    const unsigned int* tb = temp + (size_t)b * cap;
    for (int i = t; i < cntb; i += 256) {
        unsigned int ed = tb[i];
        int dstloc = (int)(ed & 1023u);
        int s = (int)(ed >> BK_SHIFT);
        atomicAdd(&cnt3[dstloc * NCHUNK + (s >> CH_SHIFT)], 1);
    }
    __syncthreads();
    // ---- per-node degree (reads counters before prefix overwrites) ----
#pragma unroll
    for (int k = 0; k < 4; ++k) {
        int idx = t * 4 + k;            // node-local 0..1023
        int d = 0;
        for (int c = 0; c < NCHUNK; ++c) d += cnt3[idx * NCHUNK + c];
        int node = nbeg + idx;
        if (node < n) {
            float fd = (float)d;
            dis[node] = (d > 0) ? rsqrtf(fd) : 0.0f;
            cnt_inv[node] = 1.0f / fmaxf(fd, 1.0f);
        }
    }
    // ---- block-wide exclusive prefix over cnt3 (13312 entries) ----
    const int PER = (KPB2 + 255) / 256;   // 52
    int my0 = t * PER;
    int run = 0;
    for (int i = 0; i < PER; ++i) {
        int idx = my0 + i;
        if (idx < KPB2) run += cnt3[idx];
    }
    __syncthreads();                      // all count reads (deg + run) done
    part[t] = run;
    __syncthreads();
    for (int off = 1; off < 256; off <<= 1) {
        int u = (t >= off) ? part[t - off] : 0;
        __syncthreads();
        part[t] += u;
        __syncthreads();
    }
    int accp = part[t] - run;             // exclusive
    for (int i = 0; i < PER; ++i) {
        int idx = my0 + i;
        if (idx < KPB2) {
            int v = cnt3[idx];
            cnt3[idx] = accp;
            accp += v;
        }
    }
    __syncthreads();
    // ---- row_ptr from key prefix (before cursors mutate) ----
#pragma unroll
    for (int k = 0; k < 4; ++k) {
        int idx = t * 4 + k;
        int node = nbeg + idx;
        if (node < n) row_ptr[node] = bbase + cnt3[idx * NCHUNK];
    }
    if (b == nbuck - 1 && t == 0) row_ptr[n] = e;
    __syncthreads();
    // ---- scatter (cursors) ----
    for (int i = t; i < cntb; i += 256) {
        unsigned int ed = tb[i];
        int dstloc = (int)(ed & 1023u);
        int s = (int)(ed >> BK_SHIFT);
        int pos = atomicAdd(&cnt3[dstloc * NCHUNK + (s >> CH_SHIFT)], 1);
        csr_src[bbase + pos] = s;
    }
}

// ---------------- propagation, float4 path (64-wide rows) ----------------
// Wave per node. lane = g*16 + l: edge slot g (0..3), feature quad l (0..15).
// EPI: 0 plain scale; 1 selu(acc*sc + r + b).
template <bool USE_W, int EPI, int TAG>
__global__ __launch_bounds__(256) void prop4_kernel(const float4* __restrict__ in4,
                                                    float4* __restrict__ out4,
                                                    const int* __restrict__ row_ptr,
                                                    const int* __restrict__ csr_src,
                                                    const float* __restrict__ dis,
                                                    const float* __restrict__ nscale,
                                                    const float4* __restrict__ r4,
                                                    const float4* __restrict__ b4,
                                                    int n) {
    int lane = threadIdx.x & 63;
    int g = lane >> 4;
    int l = lane & 15;
    int node = RFL(blockIdx.x * 4 + (threadIdx.x >> 6));
    if (node >= n) return;
    int beg = row_ptr[node];
    int end = row_ptr[node + 1];
    float4 acc = make_float4(0.f, 0.f, 0.f, 0.f);
    int j = beg;
    // 16 edges per iteration (4 float4 gathers in flight per lane)
    for (; j + 16 <= end; j += 16) {
        int s[4];
        float4 v[4];
        float w[4];
#pragma unroll
        for (int q = 0; q < 4; ++q) s[q] = csr_src[j + q * 4 + g];
#pragma unroll
        for (int q = 0; q < 4; ++q) v[q] = in4[(size_t)s[q] * 16 + l];
#pragma unroll
        for (int q = 0; q < 4; ++q) w[q] = USE_W ? dis[s[q]] : 1.0f;
#pragma unroll
        for (int q = 0; q < 4; ++q) {
            acc.x += w[q] * v[q].x;
            acc.y += w[q] * v[q].y;
            acc.z += w[q] * v[q].z;
            acc.w += w[q] * v[q].w;
        }
    }
    // 8-edge rung
    for (; j + 8 <= end; j += 8) {
        int s[2];
        float4 v[2];
        float w[2];
#pragma unroll
        for (int q = 0; q < 2; ++q) s[q] = csr_src[j + q * 4 + g];
#pragma unroll
        for (int q = 0; q < 2; ++q) v[q] = in4[(size_t)s[q] * 16 + l];
#pragma unroll
        for (int q = 0; q < 2; ++q) w[q] = USE_W ? dis[s[q]] : 1.0f;
#pragma unroll
        for (int q = 0; q < 2; ++q) {
            acc.x += w[q] * v[q].x;
            acc.y += w[q] * v[q].y;
            acc.z += w[q] * v[q].z;
            acc.w += w[q] * v[q].w;
        }
    }
    // tail: 4 edges per iteration, masked
    for (; j < end; j += 4) {
        int idx = j + g;
        bool valid = idx < end;
        int s = csr_src[valid ? idx : (end - 1)];
        float w = USE_W ? dis[s] : 1.0f;
        if (!valid) w = 0.0f;
        float4 v = in4[(size_t)s * 16 + l];
        acc.x += w * v.x;
        acc.y += w * v.y;
        acc.z += w * v.z;
        acc.w += w * v.w;
    }
    // reduce the 4 edge-slot groups
    acc.x += __shfl_xor(acc.x, 16); acc.x += __shfl_xor(acc.x, 32);
    acc.y += __shfl_xor(acc.y, 16); acc.y += __shfl_xor(acc.y, 32);
    acc.z += __shfl_xor(acc.z, 16); acc.z += __shfl_xor(acc.z, 32);
    acc.w += __shfl_xor(acc.w, 16); acc.w += __shfl_xor(acc.w, 32);
    if (g == 0) {
        float sc = nscale[node];
        float4 r = make_float4(acc.x * sc, acc.y * sc, acc.z * sc, acc.w * sc);
        if (EPI == 1) {
            float4 ra = r4[(size_t)node * 16 + l];
            float4 bb = b4[l];
            const float scale = 1.0507009873554805f;
            const float alpha = 1.6732632423543772f;
            float t0 = r.x + ra.x + bb.x;
            float t1 = r.y + ra.y + bb.y;
            float t2 = r.z + ra.z + bb.z;
            float t3 = r.w + ra.w + bb.w;
            r.x = scale * (t0 > 0.0f ? t0 : alpha * expm1f(t0));
            r.y = scale * (t1 > 0.0f ? t1 : alpha * expm1f(t1));
            r.z = scale * (t2 > 0.0f ? t2 : alpha * expm1f(t2));
            r.w = scale * (t3 > 0.0f ? t3 : alpha * expm1f(t3));
        }
        out4[(size_t)node * 16 + l] = r;
    }
}

// ---------------- 40-wide softmax prop (scalar path, 16-deep unroll) ----------------
__global__ __launch_bounds__(256) void prop_softmax_kernel(const float* __restrict__ in,
                                                           float* __restrict__ out,
                                                           const int* __restrict__ row_ptr,
                                                           const int* __restrict__ csr_src,
                                                           const float* __restrict__ nscale,
                                                           const float* __restrict__ r_add,
                                                           int n) {
    int lane = threadIdx.x & 63;
    int node = RFL(blockIdx.x * 4 + (threadIdx.x >> 6));
    if (node >= n) return;
    int beg = row_ptr[node];
    int end = row_ptr[node + 1];
    float acc = 0.0f;
    int j = beg;
    for (; j + 16 <= end; j += 16) {
        int s[16];
        float v[16];
#pragma unroll
        for (int q = 0; q < 16; ++q) s[q] = csr_src[j + q];
#pragma unroll
        for (int q = 0; q < 16; ++q) v[q] = in[(size_t)s[q] * 40 + lane];
#pragma unroll
        for (int q = 0; q < 16; ++q) acc += v[q];
    }
    for (; j + 8 <= end; j += 8) {
        int s[8];
        float v[8];
#pragma unroll
        for (int q = 0; q < 8; ++q) s[q] = csr_src[j + q];
#pragma unroll
        for (int q = 0; q < 8; ++q) v[q] = in[(size_t)s[q] * 40 + lane];
#pragma unroll
        for (int q = 0; q < 8; ++q) acc += v[q];
    }
    for (; j < end; ++j) {
        acc += in[(size_t)csr_src[j] * 40 + lane];
    }
    float t = acc * nscale[node] + ((lane < 40) ? r_add[(size_t)node * 40 + lane] : 0.0f);
    float x = (lane < 40) ? t : -INFINITY;
    float m = x;
    for (int off = 32; off; off >>= 1) m = fmaxf(m, __shfl_xor(m, off));
    float e = (lane < 40) ? __expf(x - m) : 0.0f;
    float s = e;
    for (int off = 32; off; off >>= 1) s += __shfl_xor(s, off);
    if (lane < 40) out[(size_t)node * 40 + lane] = e / s;
}

// ---------------- tiled GEMM: [outL|outR] = in(64) @ [Wl|Wr] ----------------
// Strided column ownership (col = tx + TX*c): conflict-free sW reads.
template <int OC, int CP>
__global__ __launch_bounds__(256) void gemm_kernel(const float* __restrict__ in,
                                                   const float* __restrict__ Wl,
                                                   const float* __restrict__ Wr,
                                                   const float* __restrict__ bias,
                                                   float* __restrict__ outL,
                                                   float* __restrict__ outR,
                                                   int n, int add_bias) {
    constexpr int HC = OC / 2;
    constexpr int TX = OC / CP;
    constexpr int TY = 256 / TX;
    constexpr int NPT = 64 / TY;
    constexpr int XP = 68;
    constexpr int WP = OC + 4;
    __shared__ float sXT[64 * XP];
    __shared__ float sW[64 * WP];
    int t = threadIdx.x;
    int blk = blockIdx.x;
    for (int i = 0; i < 16; ++i) {
        int idx = i * 256 + t;
        int nd = idx >> 6;
        int k = idx & 63;
        int ng = blk * 64 + nd;
        float v = in[(size_t)(ng < n ? ng : n - 1) * 64 + k];
        sXT[k * XP + nd] = v;
    }
    for (int i = t; i < 64 * HC; i += 256) {
        int k = i / HC;
        int c = i % HC;
        sW[k * WP + c] = Wl[i];
        sW[k * WP + HC + c] = Wr[i];
    }
    __syncthreads();
    int tx = t % TX;
    int ty = t / TX;
    float acc[NPT][CP];
#pragma unroll
    for (int i = 0; i < NPT; ++i)
#pragma unroll
        for (int c = 0; c < CP; ++c) acc[i][c] = 0.0f;
#pragma unroll 4
    for (int k = 0; k < 64; ++k) {
        float xv[NPT];
#pragma unroll
        for (int i = 0; i < NPT; ++i) xv[i] = sXT[k * XP + ty * NPT + i];
        float wv[CP];
#pragma unroll
        for (int c = 0; c < CP; ++c) wv[c] = sW[k * WP + tx + TX * c];
#pragma unroll
        for (int i = 0; i < NPT; ++i)
#pragma unroll
            for (int c = 0; c < CP; ++c) acc[i][c] += xv[i] * wv[c];
    }
#pragma unroll
    for (int i = 0; i < NPT; ++i) {
        int ng = blk * 64 + ty * NPT + i;
        if (ng >= n) break;
#pragma unroll
        for (int c = 0; c < CP; ++c) {
            int col = tx + TX * c;
            if (col < HC) {
                outL[(size_t)ng * HC + col] = acc[i][c];
            } else {
                float v = acc[i][c] + (add_bias ? bias[col - HC] : 0.0f);
                outR[(size_t)ng * HC + (col - HC)] = v;
            }
        }
    }
}

// ---------------- launch ----------------

extern "C" void kernel_launch(void* const* d_in, const int* in_sizes, int n_in,
                              void* d_out, int out_size, void* d_ws, size_t ws_size,
                              hipStream_t stream) {
    const float* x   = (const float*)d_in[0];
    const float* Wl1 = (const float*)d_in[1];
    const float* Wr1 = (const float*)d_in[2];
    const float* b1  = (const float*)d_in[3];
    const float* Wl2 = (const float*)d_in[4];
    const float* Wr2 = (const float*)d_in[5];
    const float* b2  = (const float*)d_in[6];
    const int* edge_src = (const int*)d_in[7];
    const int* edge_dst = (const int*)d_in[8];
    float* out = (float*)d_out;

    const int N = in_sizes[0] / 64;
    const int E = in_sizes[7];
    const int NBUCK = (N + (1 << BK_SHIFT) - 1) >> BK_SHIFT;   // 98
    size_t bufC_bytes = (size_t)N * 64 * 4;
    int cap = E / NBUCK + E / (2 * NBUCK) + 1024;              // mean + 50% + slack
    int cap_max = (int)(bufC_bytes / ((size_t)NBUCK * 4));
    if (cap > cap_max) cap = cap_max;

    size_t off = 0;
    auto carve = [&](size_t bytes) -> void* {
        void* p = (char*)d_ws + off;
        off = (off + bytes + 255) & ~(size_t)255;
        return p;
    };
    int*          row_ptr = (int*)carve((size_t)(N + 1) * 4);
    int*          bcursor = (int*)carve((size_t)NBUCK * 4);
    float*        dis     = (float*)carve((size_t)N * 4);
    float*        cnt_inv = (float*)carve((size_t)N * 4);
    int*          csr_src = (int*)carve((size_t)E * 4);
    float*        bufA    = (float*)carve((size_t)N * 64 * 4);
    float*        bufB    = (float*)carve((size_t)N * 64 * 4);
    float*        bufC    = (float*)carve(bufC_bytes);
    unsigned int* temp    = (unsigned int*)bufC;   // alias: dead before bufC written
    (void)ws_size;

    const int nb_node = (N + 3) / 4;     // 4 waves (nodes) per block
    const int nb_gemm = (N + 63) / 64;

    // CSR build (edges end up node-major, chunk-ascending within node)
    init_bcursor_kernel<<<(NBUCK + 255) / 256, 256, 0, stream>>>(bcursor, NBUCK, cap);
    partition_kernel<<<256, 256, 0, stream>>>(edge_src, edge_dst, bcursor, temp, E, NBUCK, cap);
    bucket_csr_kernel<<<NBUCK, 256, 0, stream>>>(temp, bcursor, row_ptr, dis, cnt_inv,
                                                 csr_src, N, cap, NBUCK, E);

    // KProp x2: h = S (S x)
    prop4_kernel<true, 0, 1><<<nb_node, 256, 0, stream>>>((const float4*)x, (float4*)bufA,
                                                          row_ptr, csr_src, dis, dis, nullptr, nullptr, N);
    prop4_kernel<true, 0, 2><<<nb_node, 256, 0, stream>>>((const float4*)bufA, (float4*)bufB,
                                                          row_ptr, csr_src, dis, dis, nullptr, nullptr, N);
    // [t1|r1] = h @ [Wl1|Wr1]  (t1 -> bufA, r1 -> bufC)
    gemm_kernel<128, 8><<<nb_gemm, 256, 0, stream>>>(bufB, Wl1, Wr1, nullptr, bufA, bufC, N, 0);
    // h1 = selu(mean_agg(t1) + r1 + b1) -> bufB
    prop4_kernel<false, 1, 3><<<nb_node, 256, 0, stream>>>((const float4*)bufA, (float4*)bufB,
                                                           row_ptr, csr_src, dis, cnt_inv,
                                                           (const float4*)bufC, (const float4*)b1, N);
    // [t2|r2+b2] = h1 @ [Wl2|Wr2]  (t2 -> bufA (N x 40), r2 -> bufC (N x 40))
    gemm_kernel<80, 5><<<nb_gemm, 256, 0, stream>>>(bufB, Wl2, Wr2, b2, bufA, bufC, N, 1);
    // out = softmax(mean_agg(t2) + r2)
    prop_softmax_kernel<<<nb_node, 256, 0, stream>>>(bufA, out, row_ptr, csr_src, cnt_inv, bufC, N);
}

// Round 11
// 434.434 us; speedup vs baseline: 6.0073x; 1.0683x over previous
//
#include <hip/hip_runtime.h>
#include <hip/hip_bf16.h>
#include <math.h>

// Node classifier: KProp(K=2, gcn_norm) -> SAGEConv(64->64)+selu -> SAGEConv(64->40) -> softmax
// N=100000, E=1600000, D=H=64, C=40.
//
// R11 = R10's register-gather engine with:
//   - t1/t2 (post-GEMM, pre-mean leaf tensors) stored bf16: halves gather bytes on
//     the two mean-agg passes (p0/h/h1 stay fp32 - their error would compound).
//   - CSR build reverted to node-only counting keys (R10 proved chunk keys give
//     zero fetch benefit; 1024-entry prefix instead of 13312).
//   - gemm keeps the strided-column bank-conflict fix.

#define RFL(x) __builtin_amdgcn_readfirstlane(x)
#define BK_SHIFT 10        // coarse bucket = dst>>10 (1024 nodes)
#define MAXBUCK 256

__device__ __forceinline__ float bf2f(unsigned short u) {
    return __uint_as_float((unsigned)u << 16);
}

// ---------------- CSR build ----------------

__global__ void init_bcursor_kernel(int* __restrict__ bcursor, int nbuck, int cap) {
    int i = blockIdx.x * blockDim.x + threadIdx.x;
    if (i < nbuck) bcursor[i] = i * cap;
}

// Phase 1: block-private coarse bucket partition; packed u32 (src<<10 | dst&1023).
__global__ __launch_bounds__(256) void partition_kernel(const int* __restrict__ src,
                                                        const int* __restrict__ dst,
                                                        int* __restrict__ bcursor,
                                                        unsigned int* __restrict__ temp,
                                                        int e, int nbuck, int cap) {
    __shared__ int bc[MAXBUCK];
    int t = threadIdx.x;
    int chunk = (e + gridDim.x - 1) / gridDim.x;
    int base = blockIdx.x * chunk;
    int cnt = e - base;
    if (cnt > chunk) cnt = chunk;
    if (cnt < 0) cnt = 0;
    for (int j = t; j < nbuck; j += 256) bc[j] = 0;
    __syncthreads();
    for (int i = t; i < cnt; i += 256) {
        int d = dst[base + i];
        atomicAdd(&bc[d >> BK_SHIFT], 1);
    }
    __syncthreads();
    for (int j = t; j < nbuck; j += 256) {
        int c = bc[j];
        bc[j] = (c > 0) ? atomicAdd(&bcursor[j], c) : 0;
    }
    __syncthreads();
    for (int i = t; i < cnt; i += 256) {
        int s = src[base + i];
        int d = dst[base + i];
        int bk = d >> BK_SHIFT;
        int p = atomicAdd(&bc[bk], 1);
        if (p < (bk + 1) * cap) temp[p] = ((unsigned int)s << BK_SHIFT) | (unsigned int)(d & 1023);
    }
}

// Phase 2: per-bucket counting sort by node_local + deg/dis/cnt_inv/row_ptr.
// One WG (256 thr) per bucket of 1024 nodes.
__global__ __launch_bounds__(256) void bucket_csr_kernel(const unsigned int* __restrict__ temp,
                                                         const int* __restrict__ bcursor,
                                                         int* __restrict__ row_ptr,
                                                         float* __restrict__ dis,
                                                         float* __restrict__ cnt_inv,
                                                         int* __restrict__ csr_src,
                                                         int n, int cap, int nbuck, int e) {
    __shared__ int cnt3[1024];     // counts -> exclusive prefix (cursors)
    __shared__ int part[256];
    int b = blockIdx.x;
    int t = threadIdx.x;
    int nbeg = b << BK_SHIFT;
    // ---- bbase = exclusive prefix of bucket counts ----
    int cj = 0;
    if (t < nbuck) {
        cj = bcursor[t] - t * cap;
        if (cj > cap) cj = cap;
    }
    part[t] = cj;
    __syncthreads();
    for (int off = 1; off < 256; off <<= 1) {
        int u = (t >= off) ? part[t - off] : 0;
        __syncthreads();
        part[t] += u;
        __syncthreads();
    }
    int cntb = bcursor[b] - b * cap;
    if (cntb > cap) cntb = cap;
    int bbase = part[b] - cntb;
    __syncthreads();
    // ---- zero + count ----
    for (int i = t; i < 1024; i += 256) cnt3[i] = 0;
    __syncthreads();
    const unsigned int* tb = temp + (size_t)b * cap;
    for (int i = t; i < cntb; i += 256) {
        atomicAdd(&cnt3[tb[i] & 1023u], 1);
    }
    __syncthreads();
    // ---- per-thread: 4 node counts -> deg stats + local prefix ----
    int d0 = cnt3[t * 4 + 0], d1 = cnt3[t * 4 + 1], d2 = cnt3[t * 4 + 2], d3 = cnt3[t * 4 + 3];
    int run = d0 + d1 + d2 + d3;
    int dd[4] = {d0, d1, d2, d3};
#pragma unroll
    for (int k = 0; k < 4; ++k) {
        int node = nbeg + t * 4 + k;
        if (node < n) {
            float fd = (float)dd[k];
            dis[node] = (dd[k] > 0) ? rsqrtf(fd) : 0.0f;
            cnt_inv[node] = 1.0f / fmaxf(fd, 1.0f);
        }
    }
    __syncthreads();   // all count reads done before overwrite
    part[t] = run;
    __syncthreads();
    for (int off = 1; off < 256; off <<= 1) {
        int u = (t >= off) ? part[t - off] : 0;
        __syncthreads();
        part[t] += u;
        __syncthreads();
    }
    int ex = part[t] - run;
    int oo[4];
    oo[0] = ex; oo[1] = ex + d0; oo[2] = ex + d0 + d1; oo[3] = ex + d0 + d1 + d2;
#pragma unroll
    for (int k = 0; k < 4; ++k) {
        cnt3[t * 4 + k] = oo[k];           // cursor
        int node = nbeg + t * 4 + k;
        if (node < n) row_ptr[node] = bbase + oo[k];
    }
    if (b == nbuck - 1 && t == 0) row_ptr[n] = e;
    __syncthreads();
    // ---- scatter ----
    for (int i = t; i < cntb; i += 256) {
        unsigned int ed = tb[i];
        int pos = atomicAdd(&cnt3[ed & 1023u], 1);
        csr_src[bbase + pos] = (int)(ed >> BK_SHIFT);
    }
}

// ---------------- KProp propagation, fp32 float4 path (64-wide rows) ----------------
// Wave per node. lane = g*16 + l: edge slot g (0..3), feature quad l (0..15).
template <int TAG>
__global__ __launch_bounds__(256) void prop4_kernel(const float4* __restrict__ in4,
                                                    float4* __restrict__ out4,
                                                    const int* __restrict__ row_ptr,
                                                    const int* __restrict__ csr_src,
                                                    const float* __restrict__ dis,
                                                    int n) {
    int lane = threadIdx.x & 63;
    int g = lane >> 4;
    int l = lane & 15;
    int node = RFL(blockIdx.x * 4 + (threadIdx.x >> 6));
    if (node >= n) return;
    int beg = row_ptr[node];
    int end = row_ptr[node + 1];
    float4 acc = make_float4(0.f, 0.f, 0.f, 0.f);
    int j = beg;
    for (; j + 16 <= end; j += 16) {
        int s[4];
        float4 v[4];
        float w[4];
#pragma unroll
        for (int q = 0; q < 4; ++q) s[q] = csr_src[j + q * 4 + g];
#pragma unroll
        for (int q = 0; q < 4; ++q) v[q] = in4[(size_t)s[q] * 16 + l];
#pragma unroll
        for (int q = 0; q < 4; ++q) w[q] = dis[s[q]];
#pragma unroll
        for (int q = 0; q < 4; ++q) {
            acc.x += w[q] * v[q].x;
            acc.y += w[q] * v[q].y;
            acc.z += w[q] * v[q].z;
            acc.w += w[q] * v[q].w;
        }
    }
    for (; j + 8 <= end; j += 8) {
        int s[2];
        float4 v[2];
        float w[2];
#pragma unroll
        for (int q = 0; q < 2; ++q) s[q] = csr_src[j + q * 4 + g];
#pragma unroll
        for (int q = 0; q < 2; ++q) v[q] = in4[(size_t)s[q] * 16 + l];
#pragma unroll
        for (int q = 0; q < 2; ++q) w[q] = dis[s[q]];
#pragma unroll
        for (int q = 0; q < 2; ++q) {
            acc.x += w[q] * v[q].x;
            acc.y += w[q] * v[q].y;
            acc.z += w[q] * v[q].z;
            acc.w += w[q] * v[q].w;
        }
    }
    for (; j < end; j += 4) {
        int idx = j + g;
        bool valid = idx < end;
        int s = csr_src[valid ? idx : (end - 1)];
        float w = valid ? dis[s] : 0.0f;
        float4 v = in4[(size_t)s * 16 + l];
        acc.x += w * v.x;
        acc.y += w * v.y;
        acc.z += w * v.z;
        acc.w += w * v.w;
    }
    acc.x += __shfl_xor(acc.x, 16); acc.x += __shfl_xor(acc.x, 32);
    acc.y += __shfl_xor(acc.y, 16); acc.y += __shfl_xor(acc.y, 32);
    acc.z += __shfl_xor(acc.z, 16); acc.z += __shfl_xor(acc.z, 32);
    acc.w += __shfl_xor(acc.w, 16); acc.w += __shfl_xor(acc.w, 32);
    if (g == 0) {
        float sc = dis[node];
        out4[(size_t)node * 16 + l] = make_float4(acc.x * sc, acc.y * sc, acc.z * sc, acc.w * sc);
    }
}

// ---------------- mean-agg over bf16 t1 (64-wide, 128B rows) + selu epilogue ----------------
// h1 = selu(mean(t1) + r1 + b1). lane = g*16+l; each lane reads ushort4 (4 bf16).
__global__ __launch_bounds__(256) void prop_mean_bf_kernel(const ushort4* __restrict__ in4u,
                                                           float4* __restrict__ out4,
                                                           const int* __restrict__ row_ptr,
                                                           const int* __restrict__ csr_src,
                                                           const float* __restrict__ cnt_inv,
                                                           const float4* __restrict__ r4,
                                                           const float4* __restrict__ b4,
                                                           int n) {
    int lane = threadIdx.x & 63;
    int g = lane >> 4;
    int l = lane & 15;
    int node = RFL(blockIdx.x * 4 + (threadIdx.x >> 6));
    if (node >= n) return;
    int beg = row_ptr[node];
    int end = row_ptr[node + 1];
    float4 acc = make_float4(0.f, 0.f, 0.f, 0.f);
    int j = beg;
    for (; j + 16 <= end; j += 16) {
        int s[4];
        ushort4 u[4];
#pragma unroll
        for (int q = 0; q < 4; ++q) s[q] = csr_src[j + q * 4 + g];
#pragma unroll
        for (int q = 0; q < 4; ++q) u[q] = in4u[(size_t)s[q] * 16 + l];
#pragma unroll
        for (int q = 0; q < 4; ++q) {
            acc.x += bf2f(u[q].x);
            acc.y += bf2f(u[q].y);
            acc.z += bf2f(u[q].z);
            acc.w += bf2f(u[q].w);
        }
    }
    for (; j + 8 <= end; j += 8) {
        int s[2];
        ushort4 u[2];
#pragma unroll
        for (int q = 0; q < 2; ++q) s[q] = csr_src[j + q * 4 + g];
#pragma unroll
        for (int q = 0; q < 2; ++q) u[q] = in4u[(size_t)s[q] * 16 + l];
#pragma unroll
        for (int q = 0; q < 2; ++q) {
            acc.x += bf2f(u[q].x);
            acc.y += bf2f(u[q].y);
            acc.z += bf2f(u[q].z);
            acc.w += bf2f(u[q].w);
        }
    }
    for (; j < end; j += 4) {
        int idx = j + g;
        bool valid = idx < end;
        int s = csr_src[valid ? idx : (end - 1)];
        float w = valid ? 1.0f : 0.0f;
        ushort4 u = in4u[(size_t)s * 16 + l];
        acc.x += w * bf2f(u.x);
        acc.y += w * bf2f(u.y);
        acc.z += w * bf2f(u.z);
        acc.w += w * bf2f(u.w);
    }
    acc.x += __shfl_xor(acc.x, 16); acc.x += __shfl_xor(acc.x, 32);
    acc.y += __shfl_xor(acc.y, 16); acc.y += __shfl_xor(acc.y, 32);
    acc.z += __shfl_xor(acc.z, 16); acc.z += __shfl_xor(acc.z, 32);
    acc.w += __shfl_xor(acc.w, 16); acc.w += __shfl_xor(acc.w, 32);
    if (g == 0) {
        float sc = cnt_inv[node];
        float4 ra = r4[(size_t)node * 16 + l];
        float4 bb = b4[l];
        const float scale = 1.0507009873554805f;
        const float alpha = 1.6732632423543772f;
        float t0 = acc.x * sc + ra.x + bb.x;
        float t1 = acc.y * sc + ra.y + bb.y;
        float t2 = acc.z * sc + ra.z + bb.z;
        float t3 = acc.w * sc + ra.w + bb.w;
        float4 r;
        r.x = scale * (t0 > 0.0f ? t0 : alpha * expm1f(t0));
        r.y = scale * (t1 > 0.0f ? t1 : alpha * expm1f(t1));
        r.z = scale * (t2 > 0.0f ? t2 : alpha * expm1f(t2));
        r.w = scale * (t3 > 0.0f ? t3 : alpha * expm1f(t3));
        out4[(size_t)node * 16 + l] = r;
    }
}

// ---------------- 40-wide softmax prop over bf16 t2 (80B rows) ----------------
__global__ __launch_bounds__(256) void prop_softmax_bf_kernel(const unsigned short* __restrict__ in_bf,
                                                              float* __restrict__ out,
                                                              const int* __restrict__ row_ptr,
                                                              const int* __restrict__ csr_src,
                                                              const float* __restrict__ cnt_inv,
                                                              const float* __restrict__ r_add,
                                                              int n) {
    int lane = threadIdx.x & 63;
    int node = RFL(blockIdx.x * 4 + (threadIdx.x >> 6));
    if (node >= n) return;
    int beg = row_ptr[node];
    int end = row_ptr[node + 1];
    float acc = 0.0f;
    int j = beg;
    for (; j + 16 <= end; j += 16) {
        int s[16];
        unsigned short v[16];
#pragma unroll
        for (int q = 0; q < 16; ++q) s[q] = csr_src[j + q];
#pragma unroll
        for (int q = 0; q < 16; ++q) v[q] = in_bf[(size_t)s[q] * 40 + lane];
#pragma unroll
        for (int q = 0; q < 16; ++q) acc += bf2f(v[q]);
    }
    for (; j + 8 <= end; j += 8) {
        int s[8];
        unsigned short v[8];
#pragma unroll
        for (int q = 0; q < 8; ++q) s[q] = csr_src[j + q];
#pragma unroll
        for (int q = 0; q < 8; ++q) v[q] = in_bf[(size_t)s[q] * 40 + lane];
#pragma unroll
        for (int q = 0; q < 8; ++q) acc += bf2f(v[q]);
    }
    for (; j < end; ++j) {
        acc += bf2f(in_bf[(size_t)csr_src[j] * 40 + lane]);
    }
    float t = acc * cnt_inv[node] + ((lane < 40) ? r_add[(size_t)node * 40 + lane] : 0.0f);
    float x = (lane < 40) ? t : -INFINITY;
    float m = x;
    for (int off = 32; off; off >>= 1) m = fmaxf(m, __shfl_xor(m, off));
    float e = (lane < 40) ? __expf(x - m) : 0.0f;
    float s = e;
    for (int off = 32; off; off >>= 1) s += __shfl_xor(s, off);
    if (lane < 40) out[(size_t)node * 40 + lane] = e / s;
}

// ---------------- tiled GEMM: [outL(bf16)|outR(fp32)] = in(64) @ [Wl|Wr] ----------------
// Strided column ownership (col = tx + TX*c): conflict-free sW reads.
template <int OC, int CP>
__global__ __launch_bounds__(256) void gemm_kernel(const float* __restrict__ in,
                                                   const float* __restrict__ Wl,
                                                   const float* __restrict__ Wr,
                                                   const float* __restrict__ bias,
                                                   __hip_bfloat16* __restrict__ outL,
                                                   float* __restrict__ outR,
                                                   int n, int add_bias) {
    constexpr int HC = OC / 2;
    constexpr int TX = OC / CP;
    constexpr int TY = 256 / TX;
    constexpr int NPT = 64 / TY;
    constexpr int XP = 68;
    constexpr int WP = OC + 4;
    __shared__ float sXT[64 * XP];
    __shared__ float sW[64 * WP];
    int t = threadIdx.x;
    int blk = blockIdx.x;
    for (int i = 0; i < 16; ++i) {
        int idx = i * 256 + t;
        int nd = idx >> 6;
        int k = idx & 63;
        int ng = blk * 64 + nd;
        float v = in[(size_t)(ng < n ? ng : n - 1) * 64 + k];
        sXT[k * XP + nd] = v;
    }
    for (int i = t; i < 64 * HC; i += 256) {
        int k = i / HC;
        int c = i % HC;
        sW[k * WP + c] = Wl[i];
        sW[k * WP + HC + c] = Wr[i];
    }
    __syncthreads();
    int tx = t % TX;
    int ty = t / TX;
    float acc[NPT][CP];
#pragma unroll
    for (int i = 0; i < NPT; ++i)
#pragma unroll
        for (int c = 0; c < CP; ++c) acc[i][c] = 0.0f;
#pragma unroll 4
    for (int k = 0; k < 64; ++k) {
        float xv[NPT];
#pragma unroll
        for (int i = 0; i < NPT; ++i) xv[i] = sXT[k * XP + ty * NPT + i];
        float wv[CP];
#pragma unroll
        for (int c = 0; c < CP; ++c) wv[c] = sW[k * WP + tx + TX * c];
#pragma unroll
        for (int i = 0; i < NPT; ++i)
#pragma unroll
            for (int c = 0; c < CP; ++c) acc[i][c] += xv[i] * wv[c];
    }
#pragma unroll
    for (int i = 0; i < NPT; ++i) {
        int ng = blk * 64 + ty * NPT + i;
        if (ng >= n) break;
#pragma unroll
        for (int c = 0; c < CP; ++c) {
            int col = tx + TX * c;
            if (col < HC) {
                outL[(size_t)ng * HC + col] = __float2bfloat16(acc[i][c]);
            } else {
                float v = acc[i][c] + (add_bias ? bias[col - HC] : 0.0f);
                outR[(size_t)ng * HC + (col - HC)] = v;
            }
        }
    }
}

// ---------------- launch ----------------

extern "C" void kernel_launch(void* const* d_in, const int* in_sizes, int n_in,
                              void* d_out, int out_size, void* d_ws, size_t ws_size,
                              hipStream_t stream) {
    const float* x   = (const float*)d_in[0];
    const float* Wl1 = (const float*)d_in[1];
    const float* Wr1 = (const float*)d_in[2];
    const float* b1  = (const float*)d_in[3];
    const float* Wl2 = (const float*)d_in[4];
    const float* Wr2 = (const float*)d_in[5];
    const float* b2  = (const float*)d_in[6];
    const int* edge_src = (const int*)d_in[7];
    const int* edge_dst = (const int*)d_in[8];
    float* out = (float*)d_out;

    const int N = in_sizes[0] / 64;
    const int E = in_sizes[7];
    const int NBUCK = (N + (1 << BK_SHIFT) - 1) >> BK_SHIFT;   // 98
    size_t bufC_bytes = (size_t)N * 64 * 4;
    int cap = E / NBUCK + E / (2 * NBUCK) + 1024;              // mean + 50% + slack
    int cap_max = (int)(bufC_bytes / ((size_t)NBUCK * 4));
    if (cap > cap_max) cap = cap_max;

    size_t off = 0;
    auto carve = [&](size_t bytes) -> void* {
        void* p = (char*)d_ws + off;
        off = (off + bytes + 255) & ~(size_t)255;
        return p;
    };
    int*          row_ptr = (int*)carve((size_t)(N + 1) * 4);
    int*          bcursor = (int*)carve((size_t)NBUCK * 4);
    float*        dis     = (float*)carve((size_t)N * 4);
    float*        cnt_inv = (float*)carve((size_t)N * 4);
    int*          csr_src = (int*)carve((size_t)E * 4);
    float*        bufA    = (float*)carve((size_t)N * 64 * 4);   // p0 fp32 / t1 bf16 / t2 bf16
    float*        bufB    = (float*)carve((size_t)N * 64 * 4);   // h fp32 / h1 fp32
    float*        bufC    = (float*)carve(bufC_bytes);           // temp / r1 / r2
    unsigned int* temp    = (unsigned int*)bufC;   // alias: dead before bufC written
    (void)ws_size;

    const int nb_node = (N + 3) / 4;     // 4 waves (nodes) per block
    const int nb_gemm = (N + 63) / 64;

    // CSR build
    init_bcursor_kernel<<<(NBUCK + 255) / 256, 256, 0, stream>>>(bcursor, NBUCK, cap);
    partition_kernel<<<256, 256, 0, stream>>>(edge_src, edge_dst, bcursor, temp, E, NBUCK, cap);
    bucket_csr_kernel<<<NBUCK, 256, 0, stream>>>(temp, bcursor, row_ptr, dis, cnt_inv,
                                                 csr_src, N, cap, NBUCK, E);

    // KProp x2: h = S (S x)   (fp32)
    prop4_kernel<1><<<nb_node, 256, 0, stream>>>((const float4*)x, (float4*)bufA,
                                                 row_ptr, csr_src, dis, N);
    prop4_kernel<2><<<nb_node, 256, 0, stream>>>((const float4*)bufA, (float4*)bufB,
                                                 row_ptr, csr_src, dis, N);
    // [t1(bf16)|r1] = h @ [Wl1|Wr1]  (t1 -> bufA, r1 -> bufC)
    gemm_kernel<128, 8><<<nb_gemm, 256, 0, stream>>>(bufB, Wl1, Wr1, nullptr,
                                                     (__hip_bfloat16*)bufA, bufC, N, 0);
    // h1 = selu(mean(t1) + r1 + b1) -> bufB (fp32)
    prop_mean_bf_kernel<<<nb_node, 256, 0, stream>>>((const ushort4*)bufA, (float4*)bufB,
                                                     row_ptr, csr_src, cnt_inv,
                                                     (const float4*)bufC, (const float4*)b1, N);
    // [t2(bf16)|r2+b2] = h1 @ [Wl2|Wr2]  (t2 -> bufA, r2 -> bufC)
    gemm_kernel<80, 5><<<nb_gemm, 256, 0, stream>>>(bufB, Wl2, Wr2, b2,
                                                    (__hip_bfloat16*)bufA, bufC, N, 1);
    // out = softmax(mean(t2) + r2)
    prop_softmax_bf_kernel<<<nb_node, 256, 0, stream>>>((const unsigned short*)bufA, out,
                                                        row_ptr, csr_src, cnt_inv, bufC, N);
}

// Round 12
// 399.402 us; speedup vs baseline: 6.5342x; 1.0877x over previous
//
#include <hip/hip_runtime.h>
#include <hip/hip_bf16.h>
#include <math.h>

// Node classifier: KProp(K=2, gcn_norm) -> SAGEConv(64->64)+selu -> SAGEConv(64->40) -> softmax
// N=100000, E=1600000, D=H=64, C=40.
//
// R12 = R11 with ALL gathered/streamed intermediates in bf16 (fp32 accumulate):
//   x -> xb(bf16) once; KProp passes gather 128B bf16 rows; gemm reads bf16;
//   h1 bf16. r1/r2 stay fp32 (streamed). Outputs fp32.
//   Gather working sets halve (25.6 -> 12.8 MB) on top of halved logical bytes.

#define RFL(x) __builtin_amdgcn_readfirstlane(x)
#define BK_SHIFT 10        // coarse bucket = dst>>10 (1024 nodes)
#define MAXBUCK 256

__device__ __forceinline__ float bf2f(unsigned short u) {
    return __uint_as_float((unsigned)u << 16);
}
__device__ __forceinline__ unsigned short f2bf(float f) {
    __hip_bfloat16 b = __float2bfloat16(f);   // RTN
    return *reinterpret_cast<unsigned short*>(&b);
}

// ---------------- CSR build ----------------

__global__ void init_bcursor_kernel(int* __restrict__ bcursor, int nbuck, int cap) {
    int i = blockIdx.x * blockDim.x + threadIdx.x;
    if (i < nbuck) bcursor[i] = i * cap;
}

// Phase 1: block-private coarse bucket partition; packed u32 (src<<10 | dst&1023).
__global__ __launch_bounds__(256) void partition_kernel(const int* __restrict__ src,
                                                        const int* __restrict__ dst,
                                                        int* __restrict__ bcursor,
                                                        unsigned int* __restrict__ temp,
                                                        int e, int nbuck, int cap) {
    __shared__ int bc[MAXBUCK];
    int t = threadIdx.x;
    int chunk = (e + gridDim.x - 1) / gridDim.x;
    int base = blockIdx.x * chunk;
    int cnt = e - base;
    if (cnt > chunk) cnt = chunk;
    if (cnt < 0) cnt = 0;
    for (int j = t; j < nbuck; j += 256) bc[j] = 0;
    __syncthreads();
    for (int i = t; i < cnt; i += 256) {
        int d = dst[base + i];
        atomicAdd(&bc[d >> BK_SHIFT], 1);
    }
    __syncthreads();
    for (int j = t; j < nbuck; j += 256) {
        int c = bc[j];
        bc[j] = (c > 0) ? atomicAdd(&bcursor[j], c) : 0;
    }
    __syncthreads();
    for (int i = t; i < cnt; i += 256) {
        int s = src[base + i];
        int d = dst[base + i];
        int bk = d >> BK_SHIFT;
        int p = atomicAdd(&bc[bk], 1);
        if (p < (bk + 1) * cap) temp[p] = ((unsigned int)s << BK_SHIFT) | (unsigned int)(d & 1023);
    }
}

// Phase 2: per-bucket counting sort by node_local + deg/dis/cnt_inv/row_ptr.
__global__ __launch_bounds__(256) void bucket_csr_kernel(const unsigned int* __restrict__ temp,
                                                         const int* __restrict__ bcursor,
                                                         int* __restrict__ row_ptr,
                                                         float* __restrict__ dis,
                                                         float* __restrict__ cnt_inv,
                                                         int* __restrict__ csr_src,
                                                         int n, int cap, int nbuck, int e) {
    __shared__ int cnt3[1024];
    __shared__ int part[256];
    int b = blockIdx.x;
    int t = threadIdx.x;
    int nbeg = b << BK_SHIFT;
    int cj = 0;
    if (t < nbuck) {
        cj = bcursor[t] - t * cap;
        if (cj > cap) cj = cap;
    }
    part[t] = cj;
    __syncthreads();
    for (int off = 1; off < 256; off <<= 1) {
        int u = (t >= off) ? part[t - off] : 0;
        __syncthreads();
        part[t] += u;
        __syncthreads();
    }
    int cntb = bcursor[b] - b * cap;
    if (cntb > cap) cntb = cap;
    int bbase = part[b] - cntb;
    __syncthreads();
    for (int i = t; i < 1024; i += 256) cnt3[i] = 0;
    __syncthreads();
    const unsigned int* tb = temp + (size_t)b * cap;
    for (int i = t; i < cntb; i += 256) {
        atomicAdd(&cnt3[tb[i] & 1023u], 1);
    }
    __syncthreads();
    int d0 = cnt3[t * 4 + 0], d1 = cnt3[t * 4 + 1], d2 = cnt3[t * 4 + 2], d3 = cnt3[t * 4 + 3];
    int run = d0 + d1 + d2 + d3;
    int dd[4] = {d0, d1, d2, d3};
#pragma unroll
    for (int k = 0; k < 4; ++k) {
        int node = nbeg + t * 4 + k;
        if (node < n) {
            float fd = (float)dd[k];
            dis[node] = (dd[k] > 0) ? rsqrtf(fd) : 0.0f;
            cnt_inv[node] = 1.0f / fmaxf(fd, 1.0f);
        }
    }
    __syncthreads();
    part[t] = run;
    __syncthreads();
    for (int off = 1; off < 256; off <<= 1) {
        int u = (t >= off) ? part[t - off] : 0;
        __syncthreads();
        part[t] += u;
        __syncthreads();
    }
    int ex = part[t] - run;
    int oo[4];
    oo[0] = ex; oo[1] = ex + d0; oo[2] = ex + d0 + d1; oo[3] = ex + d0 + d1 + d2;
#pragma unroll
    for (int k = 0; k < 4; ++k) {
        cnt3[t * 4 + k] = oo[k];
        int node = nbeg + t * 4 + k;
        if (node < n) row_ptr[node] = bbase + oo[k];
    }
    if (b == nbuck - 1 && t == 0) row_ptr[n] = e;
    __syncthreads();
    for (int i = t; i < cntb; i += 256) {
        unsigned int ed = tb[i];
        int pos = atomicAdd(&cnt3[ed & 1023u], 1);
        csr_src[bbase + pos] = (int)(ed >> BK_SHIFT);
    }
}

// ---------------- fp32 -> bf16 convert ----------------
__global__ void f2bf_kernel(const float4* __restrict__ in, ushort4* __restrict__ out, int n4) {
    int i = blockIdx.x * blockDim.x + threadIdx.x;
    if (i < n4) {
        float4 v = in[i];
        ushort4 u;
        u.x = f2bf(v.x); u.y = f2bf(v.y); u.z = f2bf(v.z); u.w = f2bf(v.w);
        out[i] = u;
    }
}

// ---------------- KProp propagation over bf16 rows (128B), bf16 out ----------------
// Wave per node. lane = g*16 + l: edge slot g (0..3), feature quad l (0..15).
template <int TAG>
__global__ __launch_bounds__(256) void prop4bf_kernel(const ushort4* __restrict__ in4u,
                                                      ushort4* __restrict__ out4u,
                                                      const int* __restrict__ row_ptr,
                                                      const int* __restrict__ csr_src,
                                                      const float* __restrict__ dis,
                                                      int n) {
    int lane = threadIdx.x & 63;
    int g = lane >> 4;
    int l = lane & 15;
    int node = RFL(blockIdx.x * 4 + (threadIdx.x >> 6));
    if (node >= n) return;
    int beg = row_ptr[node];
    int end = row_ptr[node + 1];
    float4 acc = make_float4(0.f, 0.f, 0.f, 0.f);
    int j = beg;
    for (; j + 16 <= end; j += 16) {
        int s[4];
        ushort4 u[4];
        float w[4];
#pragma unroll
        for (int q = 0; q < 4; ++q) s[q] = csr_src[j + q * 4 + g];
#pragma unroll
        for (int q = 0; q < 4; ++q) u[q] = in4u[(size_t)s[q] * 16 + l];
#pragma unroll
        for (int q = 0; q < 4; ++q) w[q] = dis[s[q]];
#pragma unroll
        for (int q = 0; q < 4; ++q) {
            acc.x += w[q] * bf2f(u[q].x);
            acc.y += w[q] * bf2f(u[q].y);
            acc.z += w[q] * bf2f(u[q].z);
            acc.w += w[q] * bf2f(u[q].w);
        }
    }
    for (; j + 8 <= end; j += 8) {
        int s[2];
        ushort4 u[2];
        float w[2];
#pragma unroll
        for (int q = 0; q < 2; ++q) s[q] = csr_src[j + q * 4 + g];
#pragma unroll
        for (int q = 0; q < 2; ++q) u[q] = in4u[(size_t)s[q] * 16 + l];
#pragma unroll
        for (int q = 0; q < 2; ++q) w[q] = dis[s[q]];
#pragma unroll
        for (int q = 0; q < 2; ++q) {
            acc.x += w[q] * bf2f(u[q].x);
            acc.y += w[q] * bf2f(u[q].y);
            acc.z += w[q] * bf2f(u[q].z);
            acc.w += w[q] * bf2f(u[q].w);
        }
    }
    for (; j < end; j += 4) {
        int idx = j + g;
        bool valid = idx < end;
        int s = csr_src[valid ? idx : (end - 1)];
        float w = valid ? dis[s] : 0.0f;
        ushort4 u = in4u[(size_t)s * 16 + l];
        acc.x += w * bf2f(u.x);
        acc.y += w * bf2f(u.y);
        acc.z += w * bf2f(u.z);
        acc.w += w * bf2f(u.w);
    }
    acc.x += __shfl_xor(acc.x, 16); acc.x += __shfl_xor(acc.x, 32);
    acc.y += __shfl_xor(acc.y, 16); acc.y += __shfl_xor(acc.y, 32);
    acc.z += __shfl_xor(acc.z, 16); acc.z += __shfl_xor(acc.z, 32);
    acc.w += __shfl_xor(acc.w, 16); acc.w += __shfl_xor(acc.w, 32);
    if (g == 0) {
        float sc = dis[node];
        ushort4 o;
        o.x = f2bf(acc.x * sc);
        o.y = f2bf(acc.y * sc);
        o.z = f2bf(acc.z * sc);
        o.w = f2bf(acc.w * sc);
        out4u[(size_t)node * 16 + l] = o;
    }
}

// ---------------- mean-agg over bf16 t1 + selu epilogue, bf16 out ----------------
__global__ __launch_bounds__(256) void prop_mean_bf_kernel(const ushort4* __restrict__ in4u,
                                                           ushort4* __restrict__ out4u,
                                                           const int* __restrict__ row_ptr,
                                                           const int* __restrict__ csr_src,
                                                           const float* __restrict__ cnt_inv,
                                                           const float4* __restrict__ r4,
                                                           const float4* __restrict__ b4,
                                                           int n) {
    int lane = threadIdx.x & 63;
    int g = lane >> 4;
    int l = lane & 15;
    int node = RFL(blockIdx.x * 4 + (threadIdx.x >> 6));
    if (node >= n) return;
    int beg = row_ptr[node];
    int end = row_ptr[node + 1];
    float4 acc = make_float4(0.f, 0.f, 0.f, 0.f);
    int j = beg;
    for (; j + 16 <= end; j += 16) {
        int s[4];
        ushort4 u[4];
#pragma unroll
        for (int q = 0; q < 4; ++q) s[q] = csr_src[j + q * 4 + g];
#pragma unroll
        for (int q = 0; q < 4; ++q) u[q] = in4u[(size_t)s[q] * 16 + l];
#pragma unroll
        for (int q = 0; q < 4; ++q) {
            acc.x += bf2f(u[q].x);
            acc.y += bf2f(u[q].y);
            acc.z += bf2f(u[q].z);
            acc.w += bf2f(u[q].w);
        }
    }
    for (; j + 8 <= end; j += 8) {
        int s[2];
        ushort4 u[2];
#pragma unroll
        for (int q = 0; q < 2; ++q) s[q] = csr_src[j + q * 4 + g];
#pragma unroll
        for (int q = 0; q < 2; ++q) u[q] = in4u[(size_t)s[q] * 16 + l];
#pragma unroll
        for (int q = 0; q < 2; ++q) {
            acc.x += bf2f(u[q].x);
            acc.y += bf2f(u[q].y);
            acc.z += bf2f(u[q].z);
            acc.w += bf2f(u[q].w);
        }
    }
    for (; j < end; j += 4) {
        int idx = j + g;
        bool valid = idx < end;
        int s = csr_src[valid ? idx : (end - 1)];
        float w = valid ? 1.0f : 0.0f;
        ushort4 u = in4u[(size_t)s * 16 + l];
        acc.x += w * bf2f(u.x);
        acc.y += w * bf2f(u.y);
        acc.z += w * bf2f(u.z);
        acc.w += w * bf2f(u.w);
    }
    acc.x += __shfl_xor(acc.x, 16); acc.x += __shfl_xor(acc.x, 32);
    acc.y += __shfl_xor(acc.y, 16); acc.y += __shfl_xor(acc.y, 32);
    acc.z += __shfl_xor(acc.z, 16); acc.z += __shfl_xor(acc.z, 32);
    acc.w += __shfl_xor(acc.w, 16); acc.w += __shfl_xor(acc.w, 32);
    if (g == 0) {
        float sc = cnt_inv[node];
        float4 ra = r4[(size_t)node * 16 + l];
        float4 bb = b4[l];
        const float scale = 1.0507009873554805f;
        const float alpha = 1.6732632423543772f;
        float t0 = acc.x * sc + ra.x + bb.x;
        float t1 = acc.y * sc + ra.y + bb.y;
        float t2 = acc.z * sc + ra.z + bb.z;
        float t3 = acc.w * sc + ra.w + bb.w;
        t0 = scale * (t0 > 0.0f ? t0 : alpha * expm1f(t0));
        t1 = scale * (t1 > 0.0f ? t1 : alpha * expm1f(t1));
        t2 = scale * (t2 > 0.0f ? t2 : alpha * expm1f(t2));
        t3 = scale * (t3 > 0.0f ? t3 : alpha * expm1f(t3));
        ushort4 o;
        o.x = f2bf(t0); o.y = f2bf(t1); o.z = f2bf(t2); o.w = f2bf(t3);
        out4u[(size_t)node * 16 + l] = o;
    }
}

// ---------------- 40-wide softmax prop over bf16 t2 ----------------
__global__ __launch_bounds__(256) void prop_softmax_bf_kernel(const unsigned short* __restrict__ in_bf,
                                                              float* __restrict__ out,
                                                              const int* __restrict__ row_ptr,
                                                              const int* __restrict__ csr_src,
                                                              const float* __restrict__ cnt_inv,
                                                              const float* __restrict__ r_add,
                                                              int n) {
    int lane = threadIdx.x & 63;
    int node = RFL(blockIdx.x * 4 + (threadIdx.x >> 6));
    if (node >= n) return;
    int beg = row_ptr[node];
    int end = row_ptr[node + 1];
    float acc = 0.0f;
    int j = beg;
    for (; j + 16 <= end; j += 16) {
        int s[16];
        unsigned short v[16];
#pragma unroll
        for (int q = 0; q < 16; ++q) s[q] = csr_src[j + q];
#pragma unroll
        for (int q = 0; q < 16; ++q) v[q] = in_bf[(size_t)s[q] * 40 + lane];
#pragma unroll
        for (int q = 0; q < 16; ++q) acc += bf2f(v[q]);
    }
    for (; j + 8 <= end; j += 8) {
        int s[8];
        unsigned short v[8];
#pragma unroll
        for (int q = 0; q < 8; ++q) s[q] = csr_src[j + q];
#pragma unroll
        for (int q = 0; q < 8; ++q) v[q] = in_bf[(size_t)s[q] * 40 + lane];
#pragma unroll
        for (int q = 0; q < 8; ++q) acc += bf2f(v[q]);
    }
    for (; j < end; ++j) {
        acc += bf2f(in_bf[(size_t)csr_src[j] * 40 + lane]);
    }
    float t = acc * cnt_inv[node] + ((lane < 40) ? r_add[(size_t)node * 40 + lane] : 0.0f);
    float x = (lane < 40) ? t : -INFINITY;
    float m = x;
    for (int off = 32; off; off >>= 1) m = fmaxf(m, __shfl_xor(m, off));
    float e = (lane < 40) ? __expf(x - m) : 0.0f;
    float s = e;
    for (int off = 32; off; off >>= 1) s += __shfl_xor(s, off);
    if (lane < 40) out[(size_t)node * 40 + lane] = e / s;
}

// ---------------- tiled GEMM: [outL(bf16)|outR(fp32)] = in_bf16(64) @ [Wl|Wr] ----------------
template <int OC, int CP>
__global__ __launch_bounds__(256) void gemm_kernel(const unsigned short* __restrict__ in,
                                                   const float* __restrict__ Wl,
                                                   const float* __restrict__ Wr,
                                                   const float* __restrict__ bias,
                                                   __hip_bfloat16* __restrict__ outL,
                                                   float* __restrict__ outR,
                                                   int n, int add_bias) {
    constexpr int HC = OC / 2;
    constexpr int TX = OC / CP;
    constexpr int TY = 256 / TX;
    constexpr int NPT = 64 / TY;
    constexpr int XP = 68;
    constexpr int WP = OC + 4;
    __shared__ float sXT[64 * XP];
    __shared__ float sW[64 * WP];
    int t = threadIdx.x;
    int blk = blockIdx.x;
    for (int i = 0; i < 16; ++i) {
        int idx = i * 256 + t;
        int nd = idx >> 6;
        int k = idx & 63;
        int ng = blk * 64 + nd;
        float v = bf2f(in[(size_t)(ng < n ? ng : n - 1) * 64 + k]);
        sXT[k * XP + nd] = v;
    }
    for (int i = t; i < 64 * HC; i += 256) {
        int k = i / HC;
        int c = i % HC;
        sW[k * WP + c] = Wl[i];
        sW[k * WP + HC + c] = Wr[i];
    }
    __syncthreads();
    int tx = t % TX;
    int ty = t / TX;
    float acc[NPT][CP];
#pragma unroll
    for (int i = 0; i < NPT; ++i)
#pragma unroll
        for (int c = 0; c < CP; ++c) acc[i][c] = 0.0f;
#pragma unroll 4
    for (int k = 0; k < 64; ++k) {
        float xv[NPT];
#pragma unroll
        for (int i = 0; i < NPT; ++i) xv[i] = sXT[k * XP + ty * NPT + i];
        float wv[CP];
#pragma unroll
        for (int c = 0; c < CP; ++c) wv[c] = sW[k * WP + tx + TX * c];
#pragma unroll
        for (int i = 0; i < NPT; ++i)
#pragma unroll
            for (int c = 0; c < CP; ++c) acc[i][c] += xv[i] * wv[c];
    }
#pragma unroll
    for (int i = 0; i < NPT; ++i) {
        int ng = blk * 64 + ty * NPT + i;
        if (ng >= n) break;
#pragma unroll
        for (int c = 0; c < CP; ++c) {
            int col = tx + TX * c;
            if (col < HC) {
                outL[(size_t)ng * HC + col] = __float2bfloat16(acc[i][c]);
            } else {
                float v = acc[i][c] + (add_bias ? bias[col - HC] : 0.0f);
                outR[(size_t)ng * HC + (col - HC)] = v;
            }
        }
    }
}

// ---------------- launch ----------------

extern "C" void kernel_launch(void* const* d_in, const int* in_sizes, int n_in,
                              void* d_out, int out_size, void* d_ws, size_t ws_size,
                              hipStream_t stream) {
    const float* x   = (const float*)d_in[0];
    const float* Wl1 = (const float*)d_in[1];
    const float* Wr1 = (const float*)d_in[2];
    const float* b1  = (const float*)d_in[3];
    const float* Wl2 = (const float*)d_in[4];
    const float* Wr2 = (const float*)d_in[5];
    const float* b2  = (const float*)d_in[6];
    const int* edge_src = (const int*)d_in[7];
    const int* edge_dst = (const int*)d_in[8];
    float* out = (float*)d_out;

    const int N = in_sizes[0] / 64;
    const int E = in_sizes[7];
    const int NBUCK = (N + (1 << BK_SHIFT) - 1) >> BK_SHIFT;   // 98
    size_t buf_bytes = (size_t)N * 64 * 4;
    int cap = E / NBUCK + E / (2 * NBUCK) + 1024;              // mean + 50% + slack
    int cap_max = (int)(buf_bytes / ((size_t)NBUCK * 4));
    if (cap > cap_max) cap = cap_max;

    size_t off = 0;
    auto carve = [&](size_t bytes) -> void* {
        void* p = (char*)d_ws + off;
        off = (off + bytes + 255) & ~(size_t)255;
        return p;
    };
    int*          row_ptr = (int*)carve((size_t)(N + 1) * 4);
    int*          bcursor = (int*)carve((size_t)NBUCK * 4);
    float*        dis     = (float*)carve((size_t)N * 4);
    float*        cnt_inv = (float*)carve((size_t)N * 4);
    int*          csr_src = (int*)carve((size_t)E * 4);
    char*         bufA    = (char*)carve(buf_bytes);
    char*         bufB    = (char*)carve(buf_bytes);
    float*        bufC    = (float*)carve(buf_bytes);          // temp / r1 / r2
    unsigned int* temp    = (unsigned int*)bufC;               // dead before r1 written
    (void)ws_size;

    // bf16 sub-buffers (sequenced so nothing live overlaps):
    unsigned short* xb  = (unsigned short*)bufA;                         // x bf16
    unsigned short* p0b = (unsigned short*)(bufA + buf_bytes / 2);       // p0 bf16
    unsigned short* hb  = (unsigned short*)bufB;                         // h bf16
    unsigned short* t1b = (unsigned short*)bufA;                         // t1 bf16 (xb dead)
    unsigned short* h1b = (unsigned short*)bufB;                         // h1 bf16 (hb dead)
    unsigned short* t2b = (unsigned short*)(bufA + buf_bytes / 2);       // t2 bf16 (p0b dead)

    const int nb_node = (N + 3) / 4;
    const int nb_gemm = (N + 63) / 64;
    const int n4 = N * 64 / 4;

    // CSR build
    init_bcursor_kernel<<<(NBUCK + 255) / 256, 256, 0, stream>>>(bcursor, NBUCK, cap);
    partition_kernel<<<256, 256, 0, stream>>>(edge_src, edge_dst, bcursor, temp, E, NBUCK, cap);
    bucket_csr_kernel<<<NBUCK, 256, 0, stream>>>(temp, bcursor, row_ptr, dis, cnt_inv,
                                                 csr_src, N, cap, NBUCK, E);

    // x -> bf16
    f2bf_kernel<<<(n4 + 255) / 256, 256, 0, stream>>>((const float4*)x, (ushort4*)xb, n4);
    // KProp x2: p0 = S x ; h = S p0   (bf16 rows, fp32 accumulate)
    prop4bf_kernel<1><<<nb_node, 256, 0, stream>>>((const ushort4*)xb, (ushort4*)p0b,
                                                   row_ptr, csr_src, dis, N);
    prop4bf_kernel<2><<<nb_node, 256, 0, stream>>>((const ushort4*)p0b, (ushort4*)hb,
                                                   row_ptr, csr_src, dis, N);
    // [t1(bf16)|r1(fp32)] = h @ [Wl1|Wr1]
    gemm_kernel<128, 8><<<nb_gemm, 256, 0, stream>>>(hb, Wl1, Wr1, nullptr,
                                                     (__hip_bfloat16*)t1b, bufC, N, 0);
    // h1 = selu(mean(t1) + r1 + b1) -> bf16
    prop_mean_bf_kernel<<<nb_node, 256, 0, stream>>>((const ushort4*)t1b, (ushort4*)h1b,
                                                     row_ptr, csr_src, cnt_inv,
                                                     (const float4*)bufC, (const float4*)b1, N);
    // [t2(bf16)|r2+b2(fp32)] = h1 @ [Wl2|Wr2]
    gemm_kernel<80, 5><<<nb_gemm, 256, 0, stream>>>(h1b, Wl2, Wr2, b2,
                                                    (__hip_bfloat16*)t2b, bufC, N, 1);
    // out = softmax(mean(t2) + r2)
    prop_softmax_bf_kernel<<<nb_node, 256, 0, stream>>>(t2b, out, row_ptr, csr_src,
                                                        cnt_inv, bufC, N);
}